// Round 3
// baseline (384.336 us; speedup 1.0000x reference)
//
#include <hip/hip_runtime.h>
#include <hip/hip_bf16.h>
#include <math.h>

// Problem constants
#define BATCH 8
#define LTOT 4096
#define DEMB 1024
#define NH 16
#define DH 64
#define CHUNKS 32
#define RPB 128   // rows per block (LTOT / CHUNKS)

// ws layout (float offsets)
#define WS_S     0                          // S      [B][1024][16]
#define WS_SV    (WS_S + BATCH*DEMB*NH)     // sv     [B][16]
#define WS_WQ    (WS_SV + BATCH*NH)         // wq_sw  [B][16][1024]  (transposed+swizzled)
#define WS_C     (WS_WQ + BATCH*DEMB*NH)    // c      [B][16]
#define WS_SPART (WS_C + BATCH*NH)          // Spart  [B*32][1024][16]
#define WS_NEED  ((size_t)(WS_SPART + (size_t)BATCH*CHUNKS*DEMB*NH) * 4)

// Swizzled transposed layout for a [1024][16] matrix staged as [16][1024]:
// logical (h, i) with g=i>>2, lo=i&3 lives at  h*1024 + ((g^h)<<2) + lo.
// float4 read wv4[h*256 + (g^h)] returns logical elements i=4g..4g+3.
// Bank math: group = ((g^h)%8)*4 -> 16 h values -> 2 addrs/bank-group (free).

// ---------------------------------------------------------------------------
// K1: fused v + S partials. 1024 thr, block = (b, 128-row chunk).
//   phase A: thread (rp=t>>4, h=t&15) computes v for rows {2rp, 2rp+1}
//            via b128 swizzled LDS reads (8 FMA / b128).
//   phase B: thread (i4=t>>2, hg=t&3) owns cols 4i4..+3 x heads 4hg..+3;
//            per row: 1 float4 x + 1 b128 v broadcast, 16 FMA.
// ---------------------------------------------------------------------------
__global__ __launch_bounds__(1024, 8) void k1_fused(
    const float* __restrict__ x, const float* __restrict__ Wv,
    const float* __restrict__ bv, float* __restrict__ Spart,
    float* __restrict__ S, float* __restrict__ sv, int direct) {
  __shared__ float wv_sw[DEMB * NH];   // 64 KB
  __shared__ float vt[RPB * NH];       // 8 KB
  __shared__ float sv_red[1024];       // 4 KB

  const int b = blockIdx.x >> 5;
  const int chunk = blockIdx.x & 31;
  const int l0 = chunk * RPB;
  const int t = threadIdx.x;

  // ---- stage Wv[1024][16] -> transposed+swizzled LDS (thread t = row t)
  {
    const float4* wrow = (const float4*)&Wv[(size_t)t * NH];
    const float4 r0 = wrow[0], r1 = wrow[1], r2 = wrow[2], r3 = wrow[3];
    const float vals[16] = {r0.x, r0.y, r0.z, r0.w, r1.x, r1.y, r1.z, r1.w,
                            r2.x, r2.y, r2.z, r2.w, r3.x, r3.y, r3.z, r3.w};
    const int g = t >> 2, lo = t & 3;
    #pragma unroll
    for (int h = 0; h < 16; ++h)
      wv_sw[h * DEMB + (((g ^ h) << 2) + lo)] = vals[h];
  }
  __syncthreads();

  // ---- phase A
  {
    const int h = t & 15;
    const int rp = t >> 4;   // 0..63
    const float4* x40 = (const float4*)(x + ((size_t)b * LTOT + l0 + 2 * rp) * DEMB);
    const float4* x41 = x40 + 256;
    const float4* wv4 = (const float4*)&wv_sw[h * DEMB];
    float c00 = 0.f, c01 = 0.f, c10 = 0.f, c11 = 0.f;
    #pragma unroll 4
    for (int g = 0; g < 256; ++g) {
      const float4 w = wv4[g ^ h];
      const float4 a = x40[g];
      const float4 d = x41[g];
      c00 += a.x * w.x + a.y * w.y;
      c01 += a.z * w.z + a.w * w.w;
      c10 += d.x * w.x + d.y * w.y;
      c11 += d.z * w.z + d.w * w.w;
    }
    const float bvh = bv[h];
    const float v0 = bvh + c00 + c01;
    const float v1 = bvh + c10 + c11;
    vt[(2 * rp) * NH + h] = v0;
    vt[(2 * rp + 1) * NH + h] = v1;
    sv_red[t] = v0 + v1;
  }
  __syncthreads();

  // ---- phase B
  {
    const int hg = t & 3;
    const int i4 = t >> 2;   // 0..255
    const float4* xb4 = (const float4*)(x + ((size_t)b * LTOT + l0) * DEMB);
    const float4* vt4 = (const float4*)vt;
    float4 accA = {0, 0, 0, 0}, accB = accA, accC = accA, accD = accA;
    #pragma unroll 4
    for (int l = 0; l < RPB; ++l) {
      const float4 xv = xb4[l * 256 + i4];
      const float4 vv = vt4[l * 4 + hg];
      accA.x += xv.x * vv.x; accA.y += xv.x * vv.y; accA.z += xv.x * vv.z; accA.w += xv.x * vv.w;
      accB.x += xv.y * vv.x; accB.y += xv.y * vv.y; accB.z += xv.y * vv.z; accB.w += xv.y * vv.w;
      accC.x += xv.z * vv.x; accC.y += xv.z * vv.y; accC.z += xv.z * vv.z; accC.w += xv.z * vv.w;
      accD.x += xv.w * vv.x; accD.y += xv.w * vv.y; accD.z += xv.w * vv.z; accD.w += xv.w * vv.w;
    }
    const int col0 = i4 << 2;
    if (direct) {
      float* dst = Spart + ((size_t)blockIdx.x << 14);
      *(float4*)&dst[(col0 + 0) * NH + hg * 4] = accA;
      *(float4*)&dst[(col0 + 1) * NH + hg * 4] = accB;
      *(float4*)&dst[(col0 + 2) * NH + hg * 4] = accC;
      *(float4*)&dst[(col0 + 3) * NH + hg * 4] = accD;
    } else {
      float* Sb = S + ((size_t)b << 14);
      const float4 av[4] = {accA, accB, accC, accD};
      #pragma unroll
      for (int c = 0; c < 4; ++c) {
        atomicAdd(&Sb[(col0 + c) * NH + hg * 4 + 0], av[c].x);
        atomicAdd(&Sb[(col0 + c) * NH + hg * 4 + 1], av[c].y);
        atomicAdd(&Sb[(col0 + c) * NH + hg * 4 + 2], av[c].z);
        atomicAdd(&Sb[(col0 + c) * NH + hg * 4 + 3], av[c].w);
      }
    }
  }

  // ---- sv reduction (sv_red stable since the phase-B barrier)
  if (t < 16) {
    float s = 0.f;
    #pragma unroll
    for (int rr = 0; rr < 64; ++rr) s += sv_red[rr * 16 + t];
    atomicAdd(&sv[b * NH + t], s);
  }
}

// ---------------------------------------------------------------------------
// K1b: reduce 32 chunk-partials -> S.  256 blocks x 256 thr.
// ---------------------------------------------------------------------------
__global__ __launch_bounds__(256) void k1b_reduce(
    const float* __restrict__ Spart, float* __restrict__ S) {
  const int b = blockIdx.x >> 5;
  const int seg = blockIdx.x & 31;
  #pragma unroll
  for (int k = 0; k < 2; ++k) {
    const int idx = seg * 512 + k * 256 + threadIdx.x;
    float s = 0.f;
    #pragma unroll 8
    for (int c = 0; c < CHUNKS; ++c)
      s += Spart[((size_t)(b * CHUNKS + c) << 14) + idx];
    S[((size_t)b << 14) + idx] = s;
  }
}

// ---------------------------------------------------------------------------
// K2: ktv + wq_eff (written transposed+swizzled) + c. grid B*NH, 1024 thr.
// ---------------------------------------------------------------------------
__global__ __launch_bounds__(1024) void k2_ktv_wq(
    const float* __restrict__ Wq, const float* __restrict__ bq,
    const float* __restrict__ Wk, const float* __restrict__ bk,
    const float* __restrict__ S, const float* __restrict__ sv,
    float* __restrict__ wq_sw, float* __restrict__ cvec) {
  __shared__ float part[16][DH];
  __shared__ float ktv[DH];
  const int b = blockIdx.x >> 4;
  const int h = blockIdx.x & 15;
  const int t = threadIdx.x;
  const float* Sb = S + ((size_t)b << 14);

  const int d = t & 63, seg = t >> 6;   // 16 segs x 64 i
  float p = 0.f;
  #pragma unroll 4
  for (int i = seg * 64; i < seg * 64 + 64; ++i)
    p += Wk[(size_t)i * DEMB + h * DH + d] * Sb[i * NH + h];
  part[seg][d] = p;
  __syncthreads();
  if (t < 64) {
    float s = 0.f;
    #pragma unroll
    for (int k = 0; k < 16; ++k) s += part[k][t];
    s += bk[h * DH + t] * sv[b * NH + h];
    ktv[t] = s;
  }
  __syncthreads();

  {
    const int i = t;
    const float* wrow = &Wq[(size_t)i * DEMB + h * DH];
    float s0 = 0.f, s1 = 0.f;
    #pragma unroll
    for (int dd = 0; dd < DH; dd += 8) {
      const float4 w4 = *(const float4*)&wrow[dd];
      const float4 w5 = *(const float4*)&wrow[dd + 4];
      s0 += w4.x * ktv[dd] + w4.y * ktv[dd + 1] + w4.z * ktv[dd + 2] + w4.w * ktv[dd + 3];
      s1 += w5.x * ktv[dd + 4] + w5.y * ktv[dd + 5] + w5.z * ktv[dd + 6] + w5.w * ktv[dd + 7];
    }
    // transposed + swizzled: (h, i) -> h*1024 + ((g^h)<<2) + (i&3)
    wq_sw[(size_t)b * DEMB * NH + h * DEMB + ((((i >> 2) ^ h) << 2) + (i & 3))] = s0 + s1;
  }
  if (t == 0) {
    float s = 0.f;
    for (int dd = 0; dd < DH; ++dd) s += bq[h * DH + dd] * ktv[dd];
    cvec[b * NH + h] = s;
  }
}

// ---------------------------------------------------------------------------
// K3: z = (x . wq_eff + c)/8 -> sigmoid -> mask. Same dot structure as phase A.
// ---------------------------------------------------------------------------
__global__ __launch_bounds__(1024, 8) void k3_z_sigmoid(
    const float* __restrict__ x, const int* __restrict__ mask,
    const float* __restrict__ wq_sw_g, const float* __restrict__ cvec,
    float* __restrict__ out) {
  __shared__ float wq_sw[DEMB * NH];   // 64 KB (already swizzled in global)
  __shared__ float c_lds[NH];

  const int b = blockIdx.x >> 5;
  const int chunk = blockIdx.x & 31;
  const int l0 = chunk * RPB;
  const int t = threadIdx.x;

  const float4* src = (const float4*)(wq_sw_g + (size_t)b * DEMB * NH);
  float4* dst = (float4*)wq_sw;
  #pragma unroll
  for (int j = t; j < DEMB * NH / 4; j += 1024) dst[j] = src[j];
  if (t < 16) c_lds[t] = cvec[b * NH + t];
  __syncthreads();

  const int h = t & 15;
  const int rp = t >> 4;
  const int l = l0 + 2 * rp;
  const float4* x40 = (const float4*)(x + ((size_t)b * LTOT + l) * DEMB);
  const float4* x41 = x40 + 256;
  const float4* wq4 = (const float4*)&wq_sw[h * DEMB];
  float c00 = 0.f, c01 = 0.f, c10 = 0.f, c11 = 0.f;
  #pragma unroll 4
  for (int g = 0; g < 256; ++g) {
    const float4 w = wq4[g ^ h];
    const float4 a = x40[g];
    const float4 d = x41[g];
    c00 += a.x * w.x + a.y * w.y;
    c01 += a.z * w.z + a.w * w.w;
    c10 += d.x * w.x + d.y * w.y;
    c11 += d.z * w.z + d.w * w.w;
  }
  const float cb = c_lds[h];
  const float z0 = (cb + c00 + c01) * 0.125f;
  const float z1 = (cb + c10 + c11) * 0.125f;
  float p0 = 1.f / (1.f + __expf(-z0));
  float p1 = 1.f / (1.f + __expf(-z1));
  if (mask[b * LTOT + l] == 0) p0 = 0.f;
  if (mask[b * LTOT + l + 1] == 0) p1 = 0.f;
  float* orow = out + ((size_t)(b * NH + h)) * LTOT;
  orow[l] = p0;
  orow[l + 1] = p1;
}

extern "C" void kernel_launch(void* const* d_in, const int* in_sizes, int n_in,
                              void* d_out, int out_size, void* d_ws, size_t ws_size,
                              hipStream_t stream) {
  const float* x  = (const float*)d_in[0];
  const int* mask = (const int*)d_in[1];
  const float* Wq = (const float*)d_in[2];
  const float* bq = (const float*)d_in[3];
  const float* Wk = (const float*)d_in[4];
  const float* bk = (const float*)d_in[5];
  const float* Wv = (const float*)d_in[6];
  const float* bv = (const float*)d_in[7];
  float* out = (float*)d_out;
  float* ws = (float*)d_ws;

  float* S      = ws + WS_S;
  float* sv     = ws + WS_SV;
  float* wq_sw  = ws + WS_WQ;
  float* cvec   = ws + WS_C;
  float* Spart  = ws + WS_SPART;

  const int direct = (ws_size >= WS_NEED) ? 1 : 0;

  hipMemsetAsync(sv, 0, BATCH * NH * sizeof(float), stream);
  if (!direct) hipMemsetAsync(S, 0, (size_t)BATCH * DEMB * NH * sizeof(float), stream);

  k1_fused<<<dim3(BATCH * CHUNKS), dim3(1024), 0, stream>>>(x, Wv, bv, Spart, S, sv, direct);
  if (direct)
    k1b_reduce<<<dim3(BATCH * CHUNKS), dim3(256), 0, stream>>>(Spart, S);
  k2_ktv_wq<<<dim3(BATCH * NH), dim3(1024), 0, stream>>>(Wq, bq, Wk, bk, S, sv, wq_sw, cvec);
  k3_z_sigmoid<<<dim3(BATCH * CHUNKS), dim3(1024), 0, stream>>>(x, mask, wq_sw, cvec, out);
}

// Round 4
// 375.373 us; speedup vs baseline: 1.0239x; 1.0239x over previous
//
#include <hip/hip_runtime.h>
#include <hip/hip_bf16.h>
#include <math.h>

// Problem constants
#define BATCH 8
#define LTOT 4096
#define DEMB 1024
#define NH 16
#define DH 64
#define CHUNKS 32
#define RPB 128   // rows per block (LTOT / CHUNKS)

// ws layout (float offsets)
#define WS_S     0                          // S      [B][1024][16]
#define WS_SV    (WS_S + BATCH*DEMB*NH)     // sv     [B][16]
#define WS_WQ    (WS_SV + BATCH*NH)         // wq_sw  [B][16][1024]  (transposed+swizzled)
#define WS_C     (WS_WQ + BATCH*DEMB*NH)    // c      [B][16]
#define WS_SPART (WS_C + BATCH*NH)          // Spart  [B*32][1024][16]
#define WS_NEED  ((size_t)(WS_SPART + (size_t)BATCH*CHUNKS*DEMB*NH) * 4)

// Swizzled transposed layout for a [1024][16] matrix staged as [16][1024]:
// logical (h, i) with g=i>>2, lo=i&3 lives at  h*1024 + ((g^h)<<2) + lo.
// float4 read wv4[h*256 + (g^h)] returns logical elements i=4g..4g+3.
// Note (g+128)^h == (g^h)+128 for g<128, h<16.

// ---------------------------------------------------------------------------
// K1: fused v + S partials. 1024 thr, block = (b, 128-row chunk), 1 block/CU.
// launch_bounds(1024,4): VGPR cap 128 -> deep load pipelines (latency fix).
// ---------------------------------------------------------------------------
__global__ __launch_bounds__(1024, 4) void k1_fused(
    const float* __restrict__ x, const float* __restrict__ Wv,
    const float* __restrict__ bv, float* __restrict__ Spart,
    float* __restrict__ S, float* __restrict__ sv, int direct) {
  __shared__ float wv_sw[DEMB * NH];   // 64 KB
  __shared__ float vt[RPB * NH];       // 8 KB
  __shared__ float sv_red[1024];       // 4 KB

  const int b = blockIdx.x >> 5;
  const int chunk = blockIdx.x & 31;
  const int l0 = chunk * RPB;
  const int t = threadIdx.x;

  // ---- stage Wv[1024][16] -> transposed+swizzled LDS (thread t = row t)
  {
    const float4* wrow = (const float4*)&Wv[(size_t)t * NH];
    const float4 r0 = wrow[0], r1 = wrow[1], r2 = wrow[2], r3 = wrow[3];
    const float vals[16] = {r0.x, r0.y, r0.z, r0.w, r1.x, r1.y, r1.z, r1.w,
                            r2.x, r2.y, r2.z, r2.w, r3.x, r3.y, r3.z, r3.w};
    const int g = t >> 2, lo = t & 3;
    #pragma unroll
    for (int h = 0; h < 16; ++h)
      wv_sw[h * DEMB + (((g ^ h) << 2) + lo)] = vals[h];
  }
  __syncthreads();

  // ---- phase A: thread (rp=t>>4, h=t&15) computes v for rows 2rp, 2rp+1.
  // Two g-streams (g, g+128) x unroll 4 -> ~24 outstanding float4 loads.
  {
    const int h = t & 15;
    const int rp = t >> 4;   // 0..63
    const float4* xA = (const float4*)(x + ((size_t)b * LTOT + l0 + 2 * rp) * DEMB);
    const float4* xB = xA + 256;
    const float4* wv4 = (const float4*)&wv_sw[h * DEMB];
    float cA0 = 0.f, cA1 = 0.f, cB0 = 0.f, cB1 = 0.f;
    #pragma unroll 4
    for (int g = 0; g < 128; ++g) {
      const float4 w0 = wv4[g ^ h];
      const float4 w1 = wv4[(g ^ h) + 128];
      const float4 a0 = xA[g];
      const float4 a1 = xA[g + 128];
      const float4 d0 = xB[g];
      const float4 d1 = xB[g + 128];
      cA0 += a0.x * w0.x + a0.y * w0.y + a0.z * w0.z + a0.w * w0.w;
      cA1 += a1.x * w1.x + a1.y * w1.y + a1.z * w1.z + a1.w * w1.w;
      cB0 += d0.x * w0.x + d0.y * w0.y + d0.z * w0.z + d0.w * w0.w;
      cB1 += d1.x * w1.x + d1.y * w1.y + d1.z * w1.z + d1.w * w1.w;
    }
    const float bvh = bv[h];
    const float v0 = bvh + cA0 + cA1;
    const float v1 = bvh + cB0 + cB1;
    vt[(2 * rp) * NH + h] = v0;
    vt[(2 * rp + 1) * NH + h] = v1;
    sv_red[t] = v0 + v1;
  }
  __syncthreads();

  // ---- phase B: thread (i4=t>>2, hg=t&3); two l-streams (l, l+64) x unroll 4.
  {
    const int hg = t & 3;
    const int i4 = t >> 2;   // 0..255
    const float4* xb4 = (const float4*)(x + ((size_t)b * LTOT + l0) * DEMB);
    const float4* vt4 = (const float4*)vt;
    float4 accA = {0, 0, 0, 0}, accB = accA, accC = accA, accD = accA;
    float4 acc2A = {0, 0, 0, 0}, acc2B = acc2A, acc2C = acc2A, acc2D = acc2A;
    #pragma unroll 4
    for (int l = 0; l < 64; ++l) {
      const float4 xv0 = xb4[l * 256 + i4];
      const float4 vv0 = vt4[l * 4 + hg];
      const float4 xv1 = xb4[(l + 64) * 256 + i4];
      const float4 vv1 = vt4[(l + 64) * 4 + hg];
      accA.x += xv0.x * vv0.x; accA.y += xv0.x * vv0.y; accA.z += xv0.x * vv0.z; accA.w += xv0.x * vv0.w;
      accB.x += xv0.y * vv0.x; accB.y += xv0.y * vv0.y; accB.z += xv0.y * vv0.z; accB.w += xv0.y * vv0.w;
      accC.x += xv0.z * vv0.x; accC.y += xv0.z * vv0.y; accC.z += xv0.z * vv0.z; accC.w += xv0.z * vv0.w;
      accD.x += xv0.w * vv0.x; accD.y += xv0.w * vv0.y; accD.z += xv0.w * vv0.z; accD.w += xv0.w * vv0.w;
      acc2A.x += xv1.x * vv1.x; acc2A.y += xv1.x * vv1.y; acc2A.z += xv1.x * vv1.z; acc2A.w += xv1.x * vv1.w;
      acc2B.x += xv1.y * vv1.x; acc2B.y += xv1.y * vv1.y; acc2B.z += xv1.y * vv1.z; acc2B.w += xv1.y * vv1.w;
      acc2C.x += xv1.z * vv1.x; acc2C.y += xv1.z * vv1.y; acc2C.z += xv1.z * vv1.z; acc2C.w += xv1.z * vv1.w;
      acc2D.x += xv1.w * vv1.x; acc2D.y += xv1.w * vv1.y; acc2D.z += xv1.w * vv1.z; acc2D.w += xv1.w * vv1.w;
    }
    accA.x += acc2A.x; accA.y += acc2A.y; accA.z += acc2A.z; accA.w += acc2A.w;
    accB.x += acc2B.x; accB.y += acc2B.y; accB.z += acc2B.z; accB.w += acc2B.w;
    accC.x += acc2C.x; accC.y += acc2C.y; accC.z += acc2C.z; accC.w += acc2C.w;
    accD.x += acc2D.x; accD.y += acc2D.y; accD.z += acc2D.z; accD.w += acc2D.w;

    const int col0 = i4 << 2;
    if (direct) {
      float* dst = Spart + ((size_t)blockIdx.x << 14);
      *(float4*)&dst[(col0 + 0) * NH + hg * 4] = accA;
      *(float4*)&dst[(col0 + 1) * NH + hg * 4] = accB;
      *(float4*)&dst[(col0 + 2) * NH + hg * 4] = accC;
      *(float4*)&dst[(col0 + 3) * NH + hg * 4] = accD;
    } else {
      float* Sb = S + ((size_t)b << 14);
      const float4 av[4] = {accA, accB, accC, accD};
      #pragma unroll
      for (int c = 0; c < 4; ++c) {
        atomicAdd(&Sb[(col0 + c) * NH + hg * 4 + 0], av[c].x);
        atomicAdd(&Sb[(col0 + c) * NH + hg * 4 + 1], av[c].y);
        atomicAdd(&Sb[(col0 + c) * NH + hg * 4 + 2], av[c].z);
        atomicAdd(&Sb[(col0 + c) * NH + hg * 4 + 3], av[c].w);
      }
    }
  }

  // ---- sv reduction
  if (t < 16) {
    float s = 0.f;
    #pragma unroll
    for (int rr = 0; rr < 64; ++rr) s += sv_red[rr * 16 + t];
    atomicAdd(&sv[b * NH + t], s);
  }
}

// ---------------------------------------------------------------------------
// K1b: reduce 32 chunk-partials -> S.  256 blocks x 256 thr.
// ---------------------------------------------------------------------------
__global__ __launch_bounds__(256) void k1b_reduce(
    const float* __restrict__ Spart, float* __restrict__ S) {
  const int b = blockIdx.x >> 5;
  const int seg = blockIdx.x & 31;
  #pragma unroll
  for (int k = 0; k < 2; ++k) {
    const int idx = seg * 512 + k * 256 + threadIdx.x;
    float s = 0.f;
    #pragma unroll 8
    for (int c = 0; c < CHUNKS; ++c)
      s += Spart[((size_t)(b * CHUNKS + c) << 14) + idx];
    S[((size_t)b << 14) + idx] = s;
  }
}

// ---------------------------------------------------------------------------
// K2: ktv + wq_eff (written transposed+swizzled) + c. grid B*NH, 1024 thr.
// ---------------------------------------------------------------------------
__global__ __launch_bounds__(1024) void k2_ktv_wq(
    const float* __restrict__ Wq, const float* __restrict__ bq,
    const float* __restrict__ Wk, const float* __restrict__ bk,
    const float* __restrict__ S, const float* __restrict__ sv,
    float* __restrict__ wq_sw, float* __restrict__ cvec) {
  __shared__ float part[16][DH];
  __shared__ float ktv[DH];
  const int b = blockIdx.x >> 4;
  const int h = blockIdx.x & 15;
  const int t = threadIdx.x;
  const float* Sb = S + ((size_t)b << 14);

  const int d = t & 63, seg = t >> 6;   // 16 segs x 64 i
  float p = 0.f;
  #pragma unroll 4
  for (int i = seg * 64; i < seg * 64 + 64; ++i)
    p += Wk[(size_t)i * DEMB + h * DH + d] * Sb[i * NH + h];
  part[seg][d] = p;
  __syncthreads();
  if (t < 64) {
    float s = 0.f;
    #pragma unroll
    for (int k = 0; k < 16; ++k) s += part[k][t];
    s += bk[h * DH + t] * sv[b * NH + h];
    ktv[t] = s;
  }
  __syncthreads();

  {
    const int i = t;
    const float* wrow = &Wq[(size_t)i * DEMB + h * DH];
    float s0 = 0.f, s1 = 0.f;
    #pragma unroll
    for (int dd = 0; dd < DH; dd += 8) {
      const float4 w4 = *(const float4*)&wrow[dd];
      const float4 w5 = *(const float4*)&wrow[dd + 4];
      s0 += w4.x * ktv[dd] + w4.y * ktv[dd + 1] + w4.z * ktv[dd + 2] + w4.w * ktv[dd + 3];
      s1 += w5.x * ktv[dd + 4] + w5.y * ktv[dd + 5] + w5.z * ktv[dd + 6] + w5.w * ktv[dd + 7];
    }
    wq_sw[(size_t)b * DEMB * NH + h * DEMB + ((((i >> 2) ^ h) << 2) + (i & 3))] = s0 + s1;
  }
  if (t == 0) {
    float s = 0.f;
    for (int dd = 0; dd < DH; ++dd) s += bq[h * DH + dd] * ktv[dd];
    cvec[b * NH + h] = s;
  }
}

// ---------------------------------------------------------------------------
// K3: z = (x . wq_eff + c)/8 -> sigmoid -> mask. Same pipelined dot as phase A.
// ---------------------------------------------------------------------------
__global__ __launch_bounds__(1024, 4) void k3_z_sigmoid(
    const float* __restrict__ x, const int* __restrict__ mask,
    const float* __restrict__ wq_sw_g, const float* __restrict__ cvec,
    float* __restrict__ out) {
  __shared__ float wq_sw[DEMB * NH];   // 64 KB (already swizzled in global)
  __shared__ float c_lds[NH];

  const int b = blockIdx.x >> 5;
  const int chunk = blockIdx.x & 31;
  const int l0 = chunk * RPB;
  const int t = threadIdx.x;

  const float4* src = (const float4*)(wq_sw_g + (size_t)b * DEMB * NH);
  float4* dst = (float4*)wq_sw;
  #pragma unroll
  for (int j = t; j < DEMB * NH / 4; j += 1024) dst[j] = src[j];
  if (t < 16) c_lds[t] = cvec[b * NH + t];
  __syncthreads();

  const int h = t & 15;
  const int rp = t >> 4;
  const int l = l0 + 2 * rp;
  const float4* xA = (const float4*)(x + ((size_t)b * LTOT + l) * DEMB);
  const float4* xB = xA + 256;
  const float4* wq4 = (const float4*)&wq_sw[h * DEMB];
  float cA0 = 0.f, cA1 = 0.f, cB0 = 0.f, cB1 = 0.f;
  #pragma unroll 4
  for (int g = 0; g < 128; ++g) {
    const float4 w0 = wq4[g ^ h];
    const float4 w1 = wq4[(g ^ h) + 128];
    const float4 a0 = xA[g];
    const float4 a1 = xA[g + 128];
    const float4 d0 = xB[g];
    const float4 d1 = xB[g + 128];
    cA0 += a0.x * w0.x + a0.y * w0.y + a0.z * w0.z + a0.w * w0.w;
    cA1 += a1.x * w1.x + a1.y * w1.y + a1.z * w1.z + a1.w * w1.w;
    cB0 += d0.x * w0.x + d0.y * w0.y + d0.z * w0.z + d0.w * w0.w;
    cB1 += d1.x * w1.x + d1.y * w1.y + d1.z * w1.z + d1.w * w1.w;
  }
  const float cb = c_lds[h];
  const float z0 = (cb + cA0 + cA1) * 0.125f;
  const float z1 = (cb + cB0 + cB1) * 0.125f;
  float p0 = 1.f / (1.f + __expf(-z0));
  float p1 = 1.f / (1.f + __expf(-z1));
  if (mask[b * LTOT + l] == 0) p0 = 0.f;
  if (mask[b * LTOT + l + 1] == 0) p1 = 0.f;
  float* orow = out + ((size_t)(b * NH + h)) * LTOT;
  orow[l] = p0;
  orow[l + 1] = p1;
}

extern "C" void kernel_launch(void* const* d_in, const int* in_sizes, int n_in,
                              void* d_out, int out_size, void* d_ws, size_t ws_size,
                              hipStream_t stream) {
  const float* x  = (const float*)d_in[0];
  const int* mask = (const int*)d_in[1];
  const float* Wq = (const float*)d_in[2];
  const float* bq = (const float*)d_in[3];
  const float* Wk = (const float*)d_in[4];
  const float* bk = (const float*)d_in[5];
  const float* Wv = (const float*)d_in[6];
  const float* bv = (const float*)d_in[7];
  float* out = (float*)d_out;
  float* ws = (float*)d_ws;

  float* S      = ws + WS_S;
  float* sv     = ws + WS_SV;
  float* wq_sw  = ws + WS_WQ;
  float* cvec   = ws + WS_C;
  float* Spart  = ws + WS_SPART;

  const int direct = (ws_size >= WS_NEED) ? 1 : 0;

  hipMemsetAsync(sv, 0, BATCH * NH * sizeof(float), stream);
  if (!direct) hipMemsetAsync(S, 0, (size_t)BATCH * DEMB * NH * sizeof(float), stream);

  k1_fused<<<dim3(BATCH * CHUNKS), dim3(1024), 0, stream>>>(x, Wv, bv, Spart, S, sv, direct);
  if (direct)
    k1b_reduce<<<dim3(BATCH * CHUNKS), dim3(256), 0, stream>>>(Spart, S);
  k2_ktv_wq<<<dim3(BATCH * NH), dim3(1024), 0, stream>>>(Wq, bq, Wk, bk, S, sv, wq_sw, cvec);
  k3_z_sigmoid<<<dim3(BATCH * CHUNKS), dim3(1024), 0, stream>>>(x, mask, wq_sw, cvec, out);
}